// Round 1
// 279.286 us; speedup vs baseline: 1.2694x; 1.2694x over previous
//
#include <hip/hip_runtime.h>

#define HH 512
#define WW 512
#define PLANES 96          // 32 * 3
#define RSTRIP 32          // output rows per block; grid = 3072 blocks = 12/CU demand
#define NPIX 25165824.0f   // 32*3*512*512

// Gaussian weights (sigma=1.5, K=11), symmetric; these exact constants gave absmax 0.0
#define G0 0.2660117f
#define G1 0.2130056f
#define G2 0.1093607f
#define G3 0.0360008f
#define G4 0.0075988f
#define G5 0.0010284f

#define C1F 1e-4f
#define C2F 9e-4f

// 11-deep named-scalar history (SSA values; no alloca possible)
#define DECL_HIST(Z) float Z##0=0.f,Z##1=0.f,Z##2=0.f,Z##3=0.f,Z##4=0.f,Z##5=0.f,\
                           Z##6=0.f,Z##7=0.f,Z##8=0.f,Z##9=0.f,Z##10=0.f
#define SHIFT_HIST(Z) do{Z##0=Z##1;Z##1=Z##2;Z##2=Z##3;Z##3=Z##4;Z##4=Z##5;\
                         Z##5=Z##6;Z##6=Z##7;Z##7=Z##8;Z##8=Z##9;Z##9=Z##10;}while(0)
#define VCONV(Z) fmaf(G5, Z##0+Z##10, fmaf(G4, Z##1+Z##9, fmaf(G3, Z##2+Z##8,\
                 fmaf(G2, Z##3+Z##7, fmaf(G1, Z##4+Z##6, G0*Z##5)))))

// Round 7 theory: 218us @ VALUBusy 47%, HBM 9%, L3-warm replays equally slow ->
// latency/L1-bound, not BW/VALU-bound. The 6 unaligned per-thread dwordx4
// window loads (12x lane redundancy, line splits) are the exposed-latency
// source the compiler never pipelines. Fix: cooperative coalesced row staging
// into double-buffered LDS (2 scalar global loads/thread + 10-lane halo, one
// barrier/row), stride-1 LDS window reads (conflict-free), edge branch deleted
// (halo staging zero-pads). Same fma order everywhere -> bit-exact vs prior
// absmax-0.0 kernel. TLP: RSTRIP 32 + waves_per_eu(7,8) -> 28-32 waves/CU.
__global__ __launch_bounds__(256) __attribute__((amdgpu_waves_per_eu(7, 8)))
void ssim_main(const float* __restrict__ img1,
               const float* __restrict__ img2,
               float* __restrict__ acc) {
    __shared__ float lx[2][272], ly[2][272];     // 266 used per buffer
    const int tid = threadIdx.x;
    const int c0  = blockIdx.x * 256;            // first output column of block
    const int r0  = blockIdx.y * RSTRIP;         // first output row of strip
    const int p   = blockIdx.z;                  // plane (b*3+ch)
    const size_t pb = (size_t)p * (HH * WW);

    // staged column for this thread: lds index i <-> column c0-5+i
    const int cs = c0 - 5 + tid;
    const bool in_main = (unsigned)cs < (unsigned)WW;
    const bool halo    = tid < 10;
    const bool in_halo = halo && (unsigned)(cs + 256) < (unsigned)WW;

    // row pointers at (t, cs); advanced by WW per iteration (deref is guarded)
    const float* rx = img1 + pb + (ptrdiff_t)(r0 - 5) * WW + cs;
    const float* ry = img2 + pb + (ptrdiff_t)(r0 - 5) * WW + cs;

    // histories: A=conv(u), B=conv(v), P=conv(u^2), Q=conv(v^2); u=x+y, v=x-y
    DECL_HIST(A); DECL_HIST(B); DECL_HIST(P); DECL_HIST(Q);

    float lsum = 0.f;

#pragma unroll 2
    for (int t = r0 - 5; t <= r0 + RSTRIP + 4; ++t, rx += WW, ry += WW) {
        SHIFT_HIST(A); SHIFT_HIST(B); SHIFT_HIST(P); SHIFT_HIST(Q);

        float nA = 0.f, nB = 0.f, nP = 0.f, nQ = 0.f;
        if ((unsigned)t < (unsigned)HH) {        // uniform across block
            const int buf = t & 1;               // double buffer: 1 barrier/row
            float sx = 0.f, sy = 0.f, hx = 0.f, hy = 0.f;
            if (in_main) { sx = rx[0];   sy = ry[0];   }
            if (in_halo) { hx = rx[256]; hy = ry[256]; }
            lx[buf][tid] = sx;  ly[buf][tid] = sy;
            if (halo) { lx[buf][tid + 256] = hx; ly[buf][tid + 256] = hy; }
            __syncthreads();

            const float* bx = &lx[buf][tid];     // window = bx[0..10]
            const float* by = &ly[buf][tid];
            {   // center tap (G0), same op order as prior absmax-0.0 kernel
                const float x5 = bx[5], y5 = by[5];
                const float u = x5 + y5, v = x5 - y5;
                nA = G0 * u;       nB = G0 * v;
                nP = G0 * (u * u); nQ = G0 * (v * v);
            }
#define HPAIR(KL, KR, GK) { \
            const float xl = bx[KL], yl = by[KL], xr = bx[KR], yr = by[KR]; \
            const float ul = xl + yl, vl = xl - yl, ur = xr + yr, vr = xr - yr; \
            nA = fmaf(GK, ul + ur, nA); nP = fmaf(GK, fmaf(ul, ul, ur * ur), nP); \
            nB = fmaf(GK, vl + vr, nB); nQ = fmaf(GK, fmaf(vl, vl, vr * vr), nQ); }
            HPAIR(4, 6, G1) HPAIR(3, 7, G2) HPAIR(2, 8, G3)
            HPAIR(1, 9, G4) HPAIR(0, 10, G5)
#undef HPAIR
        }
        A10 = nA; B10 = nB; P10 = nP; Q10 = nQ;

        const int s = t - 5 - r0;                // output row within strip
        if ((unsigned)s < (unsigned)RSTRIP) {    // uniform; first 10 iters warm up
            const float mu_u = VCONV(A);
            const float mu_v = VCONV(B);
            const float cu2  = VCONV(P);
            const float cv2  = VCONV(Q);
            const float a = mu_u * mu_u;
            const float b = mu_v * mu_v;
            const float musq = 0.5f  * (a + b);      // mu1^2 + mu2^2
            const float mu12 = 0.25f * (a - b);      // mu1 * mu2
            const float csq  = 0.5f  * (cu2 + cv2);  // conv(x^2) + conv(y^2)
            const float cxy  = 0.25f * (cu2 - cv2);  // conv(x*y)
            const float ssum = csq - musq;           // sigma1^2 + sigma2^2
            const float s12  = cxy - mu12;           // sigma12
            const float num = fmaf(2.f, mu12, C1F) * fmaf(2.f, s12, C2F);
            const float den = (musq + C1F) * (ssum + C2F);
            lsum += num * __builtin_amdgcn_rcpf(den);
        }
    }

    // reduction: wave shfl -> LDS -> one atomic per block
#pragma unroll
    for (int off = 32; off > 0; off >>= 1)
        lsum += __shfl_down(lsum, off, 64);
    __shared__ float ws4[4];
    const int lane = threadIdx.x & 63;
    const int wv   = threadIdx.x >> 6;
    if (lane == 0) ws4[wv] = lsum;
    __syncthreads();
    if (threadIdx.x == 0)
        atomicAdd(acc, ws4[0] + ws4[1] + ws4[2] + ws4[3]);
}

__global__ void ssim_zero(float* acc) { acc[0] = 0.f; }

__global__ void ssim_finalize(const float* __restrict__ acc, float* __restrict__ out) {
    out[0] = 1.f - acc[0] * (1.f / NPIX);
}

extern "C" void kernel_launch(void* const* d_in, const int* in_sizes, int n_in,
                              void* d_out, int out_size, void* d_ws, size_t ws_size,
                              hipStream_t stream) {
    const float* img1 = (const float*)d_in[0];
    const float* img2 = (const float*)d_in[1];
    float* out = (float*)d_out;
    float* acc = (float*)d_ws;

    ssim_zero<<<1, 1, 0, stream>>>(acc);
    dim3 grid(WW / 256, HH / RSTRIP, PLANES);  // (2, 16, 96) = 3072 blocks = 12/CU
    ssim_main<<<grid, 256, 0, stream>>>(img1, img2, acc);
    ssim_finalize<<<1, 1, 0, stream>>>(acc, out);
}

// Round 2
// 272.434 us; speedup vs baseline: 1.3014x; 1.0252x over previous
//
#include <hip/hip_runtime.h>

#define HH 512
#define WW 512
#define PLANES 96          // 32 * 3
#define RSTRIP 32          // output rows per block; grid = 3072 blocks = 12/CU demand
#define NPIX 25165824.0f   // 32*3*512*512

// Gaussian weights (sigma=1.5, K=11), symmetric; these exact constants gave absmax 0.0
#define G0 0.2660117f
#define G1 0.2130056f
#define G2 0.1093607f
#define G3 0.0360008f
#define G4 0.0075988f
#define G5 0.0010284f

#define C1F 1e-4f
#define C2F 9e-4f

typedef float v2f __attribute__((ext_vector_type(2)));
#define PKFMA(a, b, c) __builtin_elementwise_fma(a, b, c)

// packed 11-deep histories: AB = (conv(u), conv(v)), PQ = (conv(u^2), conv(v^2))
#define DECL_HIST2(Z) v2f Z##0={0,0},Z##1={0,0},Z##2={0,0},Z##3={0,0},Z##4={0,0},\
                          Z##5={0,0},Z##6={0,0},Z##7={0,0},Z##8={0,0},Z##9={0,0},Z##10={0,0}
#define SHIFT_HIST(Z) do{Z##0=Z##1;Z##1=Z##2;Z##2=Z##3;Z##3=Z##4;Z##4=Z##5;\
                         Z##5=Z##6;Z##6=Z##7;Z##7=Z##8;Z##8=Z##9;Z##9=Z##10;}while(0)
// identical per-component op order as the scalar VCONV that measured absmax 0.0
#define VCONV2(Z) PKFMA(g5, Z##0+Z##10, PKFMA(g4, Z##1+Z##9, PKFMA(g3, Z##2+Z##8,\
                  PKFMA(g2, Z##3+Z##7, PKFMA(g1, Z##4+Z##6, g0*Z##5)))))

// Round 8 theory: 153us @ VALUBusy 90% -> VALU-issue-bound (~192 slots/iter).
// (1) Stage (u,v)=(x+y,x-y) once per input pixel in LDS as float2 (kills the
//     22-op/iter U/V recompute redundancy across the 11 window threads; LDS
//     reads 22xb32 -> 11xb64, stride-8B = conflict-free).
// (2) Pack (A,B) and (P,Q) streams as float2 -> v_pk_{fma,add,mul}_f32 retire
//     2 ops/slot; history shifts become v_mov_b64. Per-component op order is
//     byte-identical to the absmax-0.0 scalar kernel -> bit-exact.
__global__ __launch_bounds__(256) __attribute__((amdgpu_waves_per_eu(6, 8)))
void ssim_main(const float* __restrict__ img1,
               const float* __restrict__ img2,
               float* __restrict__ acc) {
    __shared__ v2f luv[2][272];                  // (u,v) per staged column; 266 used
    const int tid = threadIdx.x;
    const int c0  = blockIdx.x * 256;            // first output column of block
    const int r0  = blockIdx.y * RSTRIP;         // first output row of strip
    const int p   = blockIdx.z;                  // plane (b*3+ch)
    const size_t pb = (size_t)p * (HH * WW);

    // staged column for this thread: lds index i <-> column c0-5+i
    const int cs = c0 - 5 + tid;
    const bool in_main = (unsigned)cs < (unsigned)WW;
    const bool halo    = tid < 10;
    const bool in_halo = halo && (unsigned)(cs + 256) < (unsigned)WW;

    // row pointers at (t, cs); advanced by WW per iteration (deref is guarded)
    const float* rx = img1 + pb + (ptrdiff_t)(r0 - 5) * WW + cs;
    const float* ry = img2 + pb + (ptrdiff_t)(r0 - 5) * WW + cs;

    const v2f g0 = {G0, G0}, g1 = {G1, G1}, g2 = {G2, G2},
              g3 = {G3, G3}, g4 = {G4, G4}, g5 = {G5, G5};

    DECL_HIST2(AB); DECL_HIST2(PQ);

    float lsum = 0.f;

#pragma unroll 2
    for (int t = r0 - 5; t <= r0 + RSTRIP + 4; ++t, rx += WW, ry += WW) {
        SHIFT_HIST(AB); SHIFT_HIST(PQ);

        v2f nAB = {0.f, 0.f}, nPQ = {0.f, 0.f};
        if ((unsigned)t < (unsigned)HH) {        // uniform across block
            const int buf = t & 1;               // double buffer: 1 barrier/row
            float sx = 0.f, sy = 0.f, hx = 0.f, hy = 0.f;
            if (in_main) { sx = rx[0];   sy = ry[0];   }
            if (in_halo) { hx = rx[256]; hy = ry[256]; }
            luv[buf][tid] = v2f{sx + sy, sx - sy};
            if (halo) luv[buf][tid + 256] = v2f{hx + hy, hx - hy};
            __syncthreads();

            const v2f* w = &luv[buf][tid];       // window = w[0..10]
            {   // center tap (G0), per-component identical to scalar version
                const v2f uv5 = w[5];
                nAB = g0 * uv5;
                nPQ = g0 * (uv5 * uv5);
            }
#define HPAIR(KL, KR, GK) { \
            const v2f l = w[KL], r = w[KR]; \
            nAB = PKFMA(GK, l + r, nAB); \
            nPQ = PKFMA(GK, PKFMA(l, l, r * r), nPQ); }
            HPAIR(4, 6, g1) HPAIR(3, 7, g2) HPAIR(2, 8, g3)
            HPAIR(1, 9, g4) HPAIR(0, 10, g5)
#undef HPAIR
        }
        AB10 = nAB; PQ10 = nPQ;

        const int s = t - 5 - r0;                // output row within strip
        if ((unsigned)s < (unsigned)RSTRIP) {    // uniform; first 10 iters warm up
            const v2f mu = VCONV2(AB);           // (mu_u, mu_v)
            const v2f c2 = VCONV2(PQ);           // (conv(u^2), conv(v^2))
            const float a = mu.x * mu.x;
            const float b = mu.y * mu.y;
            const float musq = 0.5f  * (a + b);      // mu1^2 + mu2^2
            const float mu12 = 0.25f * (a - b);      // mu1 * mu2
            const float csq  = 0.5f  * (c2.x + c2.y);// conv(x^2) + conv(y^2)
            const float cxy  = 0.25f * (c2.x - c2.y);// conv(x*y)
            const float ssum = csq - musq;           // sigma1^2 + sigma2^2
            const float s12  = cxy - mu12;           // sigma12
            const float num = fmaf(2.f, mu12, C1F) * fmaf(2.f, s12, C2F);
            const float den = (musq + C1F) * (ssum + C2F);
            lsum += num * __builtin_amdgcn_rcpf(den);
        }
    }

    // reduction: wave shfl -> LDS -> one atomic per block
#pragma unroll
    for (int off = 32; off > 0; off >>= 1)
        lsum += __shfl_down(lsum, off, 64);
    __shared__ float ws4[4];
    const int lane = threadIdx.x & 63;
    const int wv   = threadIdx.x >> 6;
    if (lane == 0) ws4[wv] = lsum;
    __syncthreads();
    if (threadIdx.x == 0)
        atomicAdd(acc, ws4[0] + ws4[1] + ws4[2] + ws4[3]);
}

__global__ void ssim_zero(float* acc) { acc[0] = 0.f; }

__global__ void ssim_finalize(const float* __restrict__ acc, float* __restrict__ out) {
    out[0] = 1.f - acc[0] * (1.f / NPIX);
}

extern "C" void kernel_launch(void* const* d_in, const int* in_sizes, int n_in,
                              void* d_out, int out_size, void* d_ws, size_t ws_size,
                              hipStream_t stream) {
    const float* img1 = (const float*)d_in[0];
    const float* img2 = (const float*)d_in[1];
    float* out = (float*)d_out;
    float* acc = (float*)d_ws;

    ssim_zero<<<1, 1, 0, stream>>>(acc);
    dim3 grid(WW / 256, HH / RSTRIP, PLANES);  // (2, 16, 96) = 3072 blocks = 12/CU
    ssim_main<<<grid, 256, 0, stream>>>(img1, img2, acc);
    ssim_finalize<<<1, 1, 0, stream>>>(acc, out);
}